// Round 11
// baseline (273.825 us; speedup 1.0000x reference)
//
#include <hip/hip_runtime.h>
#include <stdint.h>

typedef int v4i __attribute__((ext_vector_type(4)));

#define EPS_F32 1.1920928955078125e-07f   // np.finfo(float32).eps = 2^-23

// ---------------------------------------------------------------------------
// Fused quant kernel: blocks [0,M) do per-token X quant, blocks [M,M+DOUT)
// do per-out-channel W quant.
// ---------------------------------------------------------------------------
__global__ __launch_bounds__(256) void quant_kernel(
    const float* __restrict__ X, const float* __restrict__ W,
    const float* __restrict__ ss,
    int8_t* __restrict__ Xq, float* __restrict__ xs,
    int8_t* __restrict__ Wq, float* __restrict__ ws,
    int DIN, int M)
{
    const int bid = blockIdx.x;
    const int tid = threadIdx.x;
    const bool isX = bid < M;
    const float* row = isX ? X + (size_t)bid * DIN
                           : W + (size_t)(bid - M) * DIN;

    float4 v[4];
    float amax = 0.f;
#pragma unroll
    for (int c = 0; c < 4; ++c) {
        const int k = c * 1024 + tid * 4;
        float4 xv = *(const float4*)(row + k);
        float4 sv = *(const float4*)(ss + k);
        float4 q;
        if (isX) { q.x = xv.x / sv.x; q.y = xv.y / sv.y;
                   q.z = xv.z / sv.z; q.w = xv.w / sv.w; }
        else     { q.x = xv.x * sv.x; q.y = xv.y * sv.y;
                   q.z = xv.z * sv.z; q.w = xv.w * sv.w; }
        v[c] = q;
        amax = fmaxf(amax, fmaxf(fmaxf(fabsf(q.x), fabsf(q.y)),
                                 fmaxf(fabsf(q.z), fabsf(q.w))));
    }
    __shared__ float red[4];
    for (int off = 32; off; off >>= 1) amax = fmaxf(amax, __shfl_xor(amax, off));
    const int lane = tid & 63, w = tid >> 6;
    if (lane == 0) red[w] = amax;
    __syncthreads();
    amax = fmaxf(fmaxf(red[0], red[1]), fmaxf(red[2], red[3]));

    float scale, lo;
    if (isX) { scale = fmaxf(amax, 1e-5f) / 127.0f;      lo = -127.f; }
    else     { scale = fmaxf(amax / 127.5f, EPS_F32);    lo = -128.f; }
    if (tid == 0) { if (isX) xs[bid] = scale; else ws[bid - M] = scale; }

    int* qout = isX ? (int*)(Xq + (size_t)bid * DIN)
                    : (int*)(Wq + (size_t)(bid - M) * DIN);
#pragma unroll
    for (int c = 0; c < 4; ++c) {
        float4 q = v[c];
        int b0 = (int)fminf(fmaxf(rintf(q.x / scale), lo), 127.f);
        int b1 = (int)fminf(fmaxf(rintf(q.y / scale), lo), 127.f);
        int b2 = (int)fminf(fmaxf(rintf(q.z / scale), lo), 127.f);
        int b3 = (int)fminf(fmaxf(rintf(q.w / scale), lo), 127.f);
        qout[c * 256 + tid] = (b0 & 255) | ((b1 & 255) << 8) |
                              ((b2 & 255) << 16) | ((b3 & 255) << 24);
    }
}

// ---------------------------------------------------------------------------
// Persistent 2-tile int8 NT GEMM, 256x256 tiles, BKB=128, 8 waves (2x4),
// mfma_i32_16x16x64_i8.  Grid = 256 (1 block/CU).
//
// ROUND 11: B bypasses LDS. Only A is staged (dbuf 2 x 32 KiB); B fragments
// are loaded per-kt directly from global (L2-hot: 1 MB panel reused by both
// segs) with the EXACT layout LDS staging used to produce:
//   lane reads 16B at row bn*256+nfrag+{lane&15}, k = kt*128 + ks*64 +
//   (lane>>4)*16.  16 rows/instr within one 128B line each -> L2-friendly.
// LDS traffic/kt drops 192->128 ds_read_b128 + DMA writes halve (64->32KB):
// LDS port (~1920cy) now BELOW the MFMA floor (2613cy) -> MFMA-bound.
//
// Per kt (sync skeleton = r7/r9/r10, proven):
//   {4 A-stages(kt+1) -> buf^1}  {setprio; 64 MFMA; setprio}
//   {vmcnt(0); s_barrier}        {8 B loads(kt+1); 16 A ds_reads(kt+1)}
// Audit: vmcnt(0)+barrier publishes A stages before the post-barrier A
// reads; A-stage WAR: buf[(kt+1)&1]'s previous readers were consumed by
// MFMA before barrier(kt-1); B loads are register-only (no cross-wave
// hazard), drained by the NEXT kt's vmcnt(0) (harmless).  Last kt (pf=false)
// skips loads/reads; vmcnt(0) no-op.  Seg rollover seamless (KT even;
// rollover stages/loads target seg1 kt0; epilogue stores drain at seg1-kt0's
// vmcnt(0); acc re-zeroed between segs).
// ---------------------------------------------------------------------------
#define BM 256
#define BN 256
#define BKB 128

#define MFMA __builtin_amdgcn_mfma_i32_16x16x64_i8

__global__ __launch_bounds__(512, 2) void gemm_i8_kernel(
    const int8_t* __restrict__ Xq, const int8_t* __restrict__ Wq,
    const float* __restrict__ xs, const float* __restrict__ ws,
    const float* __restrict__ bias, float* __restrict__ Y,
    int M, int N, int K)
{
    __shared__ __align__(16) int8_t smem[65536];   // A only: 2 x 32 KiB

    const int tid  = threadIdx.x;
    const int lane = tid & 63;
    const int w    = tid >> 6;
    const int wrow = w >> 2, wcol = w & 3;

    // 256 blocks; XCD-aware: each XCD owns an 8x8 rect of the 32x16 tile grid.
    const int bid    = blockIdx.x;
    const int xcd    = bid & 7, idx = bid >> 3;        // idx in [0,32)
    const int bmBase = (xcd >> 1) * 8 + (idx >> 3);    // seg0 bm; seg1 = +4
    const int bn     = (xcd & 1) * 8 + (idx & 7);

    const int srcSwz = ((lane & 7) ^ (lane >> 3)) << 4;  // A staging source swizzle
    const int chnk0  = ((lane >> 4) ^ (lane & 7)) << 4;  // A frag read, k-slice 0
    const int chnk1  = chnk0 ^ 64;                       // k-slice 1
    const int aRB = ((wrow << 6) + (lane & 15)) << 7;    // A frag row-byte base

    auto STAGE = [&](const int8_t* gtile, int region, int rowStart) {
        const int8_t* src = gtile +
            (size_t)(rowStart + (w << 3) + (lane >> 3)) * K + srcSwz;
        __builtin_amdgcn_global_load_lds(
            (const __attribute__((address_space(1))) void*)src,
            (__attribute__((address_space(3))) void*)(smem + region + ((rowStart + (w << 3)) << 7)),
            16, 0, 0);
    };

    v4i acc[8][4] = {};
    v4i aF[8][2];      // A fragments of current kt
    v4i bF[4][2];      // B fragments of current kt (direct-from-global)

    const int KT = K / BKB;   // 32
    const int rowb = (lane >> 4) << 2;
    const int col  = lane & 15;

    // B fragment base pointers (per-lane); frag nj covers output cols
    // bn*256 + (nj>>1)*128 + wcol*32 + (nj&1)*16 + (lane&15).
    const int8_t* bP[4];
#pragma unroll
    for (int nj = 0; nj < 4; ++nj)
        bP[nj] = Wq + (size_t)(bn * BN + ((nj >> 1) << 7) + (wcol << 5)
                               + ((nj & 1) << 4) + (lane & 15)) * K
                    + ((lane >> 4) << 4);

    // prologue: stage A(seg0,kt0) into buf0; load B(kt0); read A frags(kt0)
    {
        const int8_t* aT0 = Xq + (size_t)bmBase * BM * K;
        STAGE(aT0, 0, 0);  STAGE(aT0, 0, 64);
        STAGE(aT0, 0, 128); STAGE(aT0, 0, 192);
#pragma unroll
        for (int nj = 0; nj < 4; ++nj) {
            bF[nj][0] = *(const v4i*)(bP[nj]);
            bF[nj][1] = *(const v4i*)(bP[nj] + 64);
        }
        asm volatile("s_waitcnt vmcnt(0)" ::: "memory");
        __builtin_amdgcn_s_barrier();
#pragma unroll
        for (int mi = 0; mi < 8; ++mi) {
            const int moff = ((mi >> 2) << 14) + ((mi & 3) << 11);
            aF[mi][0] = *(const v4i*)(smem + aRB + moff + chnk0);
            aF[mi][1] = *(const v4i*)(smem + aRB + moff + chnk1);
        }
    }

    for (int seg = 0; seg < 2; ++seg) {
        const int bm = bmBase + seg * 4;
        const int8_t* aT0 = Xq + (size_t)bm * BM * K;

        for (int kt = 0; kt < KT; ++kt) {
            const int nAb = ((kt & 1) ^ 1) * 32768;
            const bool more = (kt + 1 < KT);
            const bool pf   = more || (seg == 0);
            const int8_t* aTn = more ? aT0 + (size_t)(kt + 1) * BKB
                                     : Xq + (size_t)(bmBase + 4) * BM * K;
            const size_t bOff = more ? (size_t)(kt + 1) * BKB : 0;

            // ---- stage A(kt+1) into buf^1
            if (pf) { STAGE(aTn, nAb, 0);   STAGE(aTn, nAb, 64);
                      STAGE(aTn, nAb, 128); STAGE(aTn, nAb, 192); }

            // ---- 64 MFMA on current fragments
            __builtin_amdgcn_s_setprio(1);
#pragma unroll
            for (int mi = 0; mi < 8; ++mi)
#pragma unroll
                for (int nj = 0; nj < 4; ++nj) {
                    acc[mi][nj] = MFMA(aF[mi][0], bF[nj][0], acc[mi][nj], 0, 0, 0);
                    acc[mi][nj] = MFMA(aF[mi][1], bF[nj][1], acc[mi][nj], 0, 0, 0);
                }
            __builtin_amdgcn_s_setprio(0);

            // ---- the per-kt sync: A stages landed, buffer swap published
            asm volatile("s_waitcnt vmcnt(0)" ::: "memory");
            __builtin_amdgcn_s_barrier();

            // ---- load next B frags (global/L2) and next A frags (LDS)
            if (pf) {
#pragma unroll
                for (int nj = 0; nj < 4; ++nj) {
                    bF[nj][0] = *(const v4i*)(bP[nj] + bOff);
                    bF[nj][1] = *(const v4i*)(bP[nj] + bOff + 64);
                }
#pragma unroll
                for (int mi = 0; mi < 8; ++mi) {
                    const int moff = ((mi >> 2) << 14) + ((mi & 3) << 11);
                    aF[mi][0] = *(const v4i*)(smem + nAb + aRB + moff + chnk0);
                    aF[mi][1] = *(const v4i*)(smem + nAb + aRB + moff + chnk1);
                }
            }
        }

        // ----- epilogue: dequant + bias (layout col=lane&15, row=(lane>>4)*4+reg)
        {
            float wsv[4], bv[4];
#pragma unroll
            for (int j = 0; j < 4; ++j) {
                const int n = bn * BN + ((j >> 1) << 7) + (wcol << 5) + ((j & 1) << 4) + col;
                wsv[j] = ws[n];
                bv[j]  = bias[n];
            }
#pragma unroll
            for (int i = 0; i < 8; ++i) {
                const int mbase = bm * BM + ((i >> 2) << 7) + (wrow << 6) + ((i & 3) << 4) + rowb;
#pragma unroll
                for (int r = 0; r < 4; ++r) {
                    const int m = mbase + r;
                    const float xsm = xs[m];
                    float* yrow = Y + (size_t)m * N;
#pragma unroll
                    for (int j = 0; j < 4; ++j) {
                        const int n = bn * BN + ((j >> 1) << 7) + (wcol << 5) + ((j & 1) << 4) + col;
                        yrow[n] = (float)acc[i][j][r] * xsm * wsv[j] + bv[j];
                    }
                }
            }
        }

        if (seg == 0) {
#pragma unroll
            for (int i = 0; i < 8; ++i)
#pragma unroll
                for (int j = 0; j < 4; ++j)
                    acc[i][j] = (v4i){0, 0, 0, 0};
        }
    }
}

// ---------------------------------------------------------------------------
extern "C" void kernel_launch(void* const* d_in, const int* in_sizes, int n_in,
                              void* d_out, int out_size, void* d_ws, size_t ws_size,
                              hipStream_t stream) {
    const float* X    = (const float*)d_in[0];
    const float* W    = (const float*)d_in[1];
    const float* bias = (const float*)d_in[2];
    const float* ss   = (const float*)d_in[3];

    const int DIN  = in_sizes[3];              // 4096
    const int DOUT = in_sizes[2];              // 4096
    const int M    = in_sizes[0] / DIN;        // 8192

    int8_t* Xq = (int8_t*)d_ws;
    int8_t* Wq = Xq + (size_t)M * DIN;
    float*  xs = (float*)(Wq + (size_t)DOUT * DIN);
    float*  ws = xs + M;
    float*  Y  = (float*)d_out;

    quant_kernel<<<M + DOUT, 256, 0, stream>>>(X, W, ss, Xq, xs, Wq, ws, DIN, M);
    gemm_i8_kernel<<<(M / BM) * (DOUT / BN) / 2, 512, 0, stream>>>(Xq, Wq, xs, ws, bias, Y, M, DOUT, DIN);
}

// Round 12
// 184.076 us; speedup vs baseline: 1.4876x; 1.4876x over previous
//
#include <hip/hip_runtime.h>
#include <stdint.h>

typedef int v4i __attribute__((ext_vector_type(4)));

#define EPS_F32 1.1920928955078125e-07f   // np.finfo(float32).eps = 2^-23

// ---------------------------------------------------------------------------
// Fused quant kernel: blocks [0,M) do per-token X quant, blocks [M,M+DOUT)
// do per-out-channel W quant.
// ---------------------------------------------------------------------------
__global__ __launch_bounds__(256) void quant_kernel(
    const float* __restrict__ X, const float* __restrict__ W,
    const float* __restrict__ ss,
    int8_t* __restrict__ Xq, float* __restrict__ xs,
    int8_t* __restrict__ Wq, float* __restrict__ ws,
    int DIN, int M)
{
    const int bid = blockIdx.x;
    const int tid = threadIdx.x;
    const bool isX = bid < M;
    const float* row = isX ? X + (size_t)bid * DIN
                           : W + (size_t)(bid - M) * DIN;

    float4 v[4];
    float amax = 0.f;
#pragma unroll
    for (int c = 0; c < 4; ++c) {
        const int k = c * 1024 + tid * 4;
        float4 xv = *(const float4*)(row + k);
        float4 sv = *(const float4*)(ss + k);
        float4 q;
        if (isX) { q.x = xv.x / sv.x; q.y = xv.y / sv.y;
                   q.z = xv.z / sv.z; q.w = xv.w / sv.w; }
        else     { q.x = xv.x * sv.x; q.y = xv.y * sv.y;
                   q.z = xv.z * sv.z; q.w = xv.w * sv.w; }
        v[c] = q;
        amax = fmaxf(amax, fmaxf(fmaxf(fabsf(q.x), fabsf(q.y)),
                                 fmaxf(fabsf(q.z), fabsf(q.w))));
    }
    __shared__ float red[4];
    for (int off = 32; off; off >>= 1) amax = fmaxf(amax, __shfl_xor(amax, off));
    const int lane = tid & 63, w = tid >> 6;
    if (lane == 0) red[w] = amax;
    __syncthreads();
    amax = fmaxf(fmaxf(red[0], red[1]), fmaxf(red[2], red[3]));

    float scale, lo;
    if (isX) { scale = fmaxf(amax, 1e-5f) / 127.0f;      lo = -127.f; }
    else     { scale = fmaxf(amax / 127.5f, EPS_F32);    lo = -128.f; }
    if (tid == 0) { if (isX) xs[bid] = scale; else ws[bid - M] = scale; }

    int* qout = isX ? (int*)(Xq + (size_t)bid * DIN)
                    : (int*)(Wq + (size_t)(bid - M) * DIN);
#pragma unroll
    for (int c = 0; c < 4; ++c) {
        float4 q = v[c];
        int b0 = (int)fminf(fmaxf(rintf(q.x / scale), lo), 127.f);
        int b1 = (int)fminf(fmaxf(rintf(q.y / scale), lo), 127.f);
        int b2 = (int)fminf(fmaxf(rintf(q.z / scale), lo), 127.f);
        int b3 = (int)fminf(fmaxf(rintf(q.w / scale), lo), 127.f);
        qout[c * 256 + tid] = (b0 & 255) | ((b1 & 255) << 8) |
                              ((b2 & 255) << 16) | ((b3 & 255) << 24);
    }
}

// ---------------------------------------------------------------------------
// Persistent 2-tile int8 NT GEMM, 256x256 tiles, BKB=128, 8 waves (2x4),
// 128 KiB dbuf LDS, mfma_i32_16x16x64_i8.  Grid = 256 (1 block/CU).
//
// ROUND 12: fine-phase schedule (m201/m196 discipline): 4 phases per kt128,
// each {reads feeding the NEXT phase's MFMA -> s_barrier -> 16 MFMA}.
// Reads issue BEFORE each barrier, so early waves' reads drain while late
// waves are still in their MFMA cluster (the cross-wave LDS||MFMA overlap
// that coarse 1-barrier/kt lockstep forbids).  Fragment sets per kt:
//   aL/aH = A m-frags 0..7, K-chunk 0/1;  bL/bH = B n-frags 0..3, chunk 0/1.
// kt body (buf c = kt&1, staging into buf n):
//   [S]  8 stages -> buf[n]
//   [R0] read aH(c)[0..3], bH(c)[0,1]     (B0) barrier
//   [M0] MFMA acc[*][0,1] += aL x bL      (K 0..63,  n-lo)
//   [R1] read aH(c)[4..7], bH(c)[2,3]     (B1) barrier
//   [M1] MFMA acc[*][2,3] += aL x bL'     (K 0..63,  n-hi)
//   [V]  vmcnt(0)  (8 stages issued ~1400cy ago -> buf[n] published)
//        (B2) barrier
//   [R2] read aL'(n)[0..7], bL'(n)[0..3]  (12 reads of published buf[n])
//   [M2] MFMA acc[*][0,1] += aH x bH      (K 64..127, n-lo)
//        (B3) barrier
//   [M3] MFMA acc[*][2,3] += aH x bH'     (K 64..127, n-hi)
// Hazard audit: M2 consumes ALL R0/R1 reads -> compiler lgkm-wait before M2
// => every wave's cur-buf reads are RETURNED before it reaches B3; the next
// kt's [S] (which overwrites buf[c]) issues after B3 => no read/DMA race.
// R2 reads buf[n] after V+B2 (published); consumed by next kt's M0/M1 whose
// waits complete before next kt's B2; buf[n] next overwritten 4+ barriers
// later.  vmcnt(0) only (no counted-N edge cases); last kt pf=false skips
// S/R2 (vmcnt no-op); KT=32 even => seamless seg rollover (rollover stages
// target seg1-kt0; epilogue stores drain at seg1-kt0's V).
// ---------------------------------------------------------------------------
#define BM 256
#define BN 256
#define BKB 128

#define MFMA __builtin_amdgcn_mfma_i32_16x16x64_i8

__global__ __launch_bounds__(512, 2) void gemm_i8_kernel(
    const int8_t* __restrict__ Xq, const int8_t* __restrict__ Wq,
    const float* __restrict__ xs, const float* __restrict__ ws,
    const float* __restrict__ bias, float* __restrict__ Y,
    int M, int N, int K)
{
    __shared__ __align__(16) int8_t smem[131072];

    const int tid  = threadIdx.x;
    const int lane = tid & 63;
    const int w    = tid >> 6;
    const int wrow = w >> 2, wcol = w & 3;

    // 256 blocks; XCD-aware: each XCD owns an 8x8 rect of the 32x16 tile grid.
    const int bid    = blockIdx.x;
    const int xcd    = bid & 7, idx = bid >> 3;        // idx in [0,32)
    const int bmBase = (xcd >> 1) * 8 + (idx >> 3);    // seg0 bm; seg1 = +4
    const int bn     = (xcd & 1) * 8 + (idx & 7);

    const int srcSwz = ((lane & 7) ^ (lane >> 3)) << 4;  // staging source swizzle
    const int chnk0  = ((lane >> 4) ^ (lane & 7)) << 4;  // frag read, k-slice 0
    const int chnk1  = chnk0 ^ 64;                       // k-slice 1
    const int aRB = ((wrow << 6) + (lane & 15)) << 7;    // A frag row-byte base
    const int bRB = ((wcol << 5) + (lane & 15)) << 7;    // B frag row-byte base

    auto STAGE = [&](const int8_t* gtile, int region, int rowStart) {
        const int8_t* src = gtile +
            (size_t)(rowStart + (w << 3) + (lane >> 3)) * K + srcSwz;
        __builtin_amdgcn_global_load_lds(
            (const __attribute__((address_space(1))) void*)src,
            (__attribute__((address_space(3))) void*)(smem + region + ((rowStart + (w << 3)) << 7)),
            16, 0, 0);
    };

    v4i acc[8][4] = {};
    v4i aL[8], aH[8], bL[4], bH[4];

    const int KT = K / BKB;   // 32
    const int8_t* bT0 = Wq + (size_t)bn * BN * K;   // same B panel both segs
    const int rowb = (lane >> 4) << 2;
    const int col  = lane & 15;

    // A frag byte offset within half-buffer, for m-frag mi:
    //   (mi>>2)*16384 + (mi&3)*2048 ; B frag nj: (nj>>1)*16384 + (nj&1)*2048
#define AOFF(mi) (((mi) >> 2) << 14) + ((((mi) & 3)) << 11)
#define BOFF(nj) (((nj) >> 1) << 14) + ((((nj) & 1)) << 11)

    // prologue: stage tile (seg0,kt0) into buf0; read aL/bL of buf0
    {
        const int8_t* aT0 = Xq + (size_t)bmBase * BM * K;
        STAGE(aT0, 0,     0);   STAGE(aT0, 0,     64);
        STAGE(aT0, 0,     128); STAGE(aT0, 0,     192);
        STAGE(bT0, 32768, 0);   STAGE(bT0, 32768, 64);
        STAGE(bT0, 32768, 128); STAGE(bT0, 32768, 192);
        asm volatile("s_waitcnt vmcnt(0)" ::: "memory");
        __builtin_amdgcn_s_barrier();
#pragma unroll
        for (int mi = 0; mi < 8; ++mi)
            aL[mi] = *(const v4i*)(smem + aRB + AOFF(mi) + chnk0);
#pragma unroll
        for (int nj = 0; nj < 4; ++nj)
            bL[nj] = *(const v4i*)(smem + 32768 + bRB + BOFF(nj) + chnk0);
    }

    for (int seg = 0; seg < 2; ++seg) {
        const int bm = bmBase + seg * 4;
        const int8_t* aT0 = Xq + (size_t)bm * BM * K;

        for (int kt = 0; kt < KT; ++kt) {
            const int Ab  = (kt & 1) * 65536;
            const int Bb  = Ab + 32768;
            const int nAb = ((kt & 1) ^ 1) * 65536;
            const int nBb = nAb + 32768;
            const bool more = (kt + 1 < KT);
            const bool pf   = more || (seg == 0);
            const int8_t* aTn = more ? aT0 + (size_t)(kt + 1) * BKB
                                     : Xq + (size_t)(bmBase + 4) * BM * K;
            const int8_t* bTn = more ? bT0 + (size_t)(kt + 1) * BKB : bT0;

            // ---- [S] 8 stages -> buf[n]
            if (pf) { STAGE(aTn, nAb, 0);   STAGE(aTn, nAb, 64);
                      STAGE(aTn, nAb, 128); STAGE(aTn, nAb, 192);
                      STAGE(bTn, nBb, 0);   STAGE(bTn, nBb, 64);
                      STAGE(bTn, nBb, 128); STAGE(bTn, nBb, 192); }

            // ---- [R0] aH[0..3], bH[0,1]   (feeds M2)
#pragma unroll
            for (int mi = 0; mi < 4; ++mi)
                aH[mi] = *(const v4i*)(smem + Ab + aRB + AOFF(mi) + chnk1);
            bH[0] = *(const v4i*)(smem + Bb + bRB + BOFF(0) + chnk1);
            bH[1] = *(const v4i*)(smem + Bb + bRB + BOFF(1) + chnk1);
            __builtin_amdgcn_s_barrier();                       // (B0)
            // ---- [M0] K-lo, n-lo
            __builtin_amdgcn_s_setprio(1);
#pragma unroll
            for (int mi = 0; mi < 8; ++mi) {
                acc[mi][0] = MFMA(aL[mi], bL[0], acc[mi][0], 0, 0, 0);
                acc[mi][1] = MFMA(aL[mi], bL[1], acc[mi][1], 0, 0, 0);
            }
            __builtin_amdgcn_s_setprio(0);

            // ---- [R1] aH[4..7], bH[2,3]   (feeds M2/M3)
#pragma unroll
            for (int mi = 4; mi < 8; ++mi)
                aH[mi] = *(const v4i*)(smem + Ab + aRB + AOFF(mi) + chnk1);
            bH[2] = *(const v4i*)(smem + Bb + bRB + BOFF(2) + chnk1);
            bH[3] = *(const v4i*)(smem + Bb + bRB + BOFF(3) + chnk1);
            __builtin_amdgcn_s_barrier();                       // (B1)
            // ---- [M1] K-lo, n-hi
            __builtin_amdgcn_s_setprio(1);
#pragma unroll
            for (int mi = 0; mi < 8; ++mi) {
                acc[mi][2] = MFMA(aL[mi], bL[2], acc[mi][2], 0, 0, 0);
                acc[mi][3] = MFMA(aL[mi], bL[3], acc[mi][3], 0, 0, 0);
            }
            __builtin_amdgcn_s_setprio(0);

            // ---- [V] publish buf[n]
            asm volatile("s_waitcnt vmcnt(0)" ::: "memory");
            __builtin_amdgcn_s_barrier();                       // (B2)

            // ---- [R2] next-kt aL/bL from buf[n]  (feeds next M0/M1)
            if (pf) {
#pragma unroll
                for (int mi = 0; mi < 8; ++mi)
                    aL[mi] = *(const v4i*)(smem + nAb + aRB + AOFF(mi) + chnk0);
#pragma unroll
                for (int nj = 0; nj < 4; ++nj)
                    bL[nj] = *(const v4i*)(smem + nBb + bRB + BOFF(nj) + chnk0);
            }
            // ---- [M2] K-hi, n-lo (consumes ALL R0/R1 -> lgkm drained here)
            __builtin_amdgcn_s_setprio(1);
#pragma unroll
            for (int mi = 0; mi < 8; ++mi) {
                acc[mi][0] = MFMA(aH[mi], bH[0], acc[mi][0], 0, 0, 0);
                acc[mi][1] = MFMA(aH[mi], bH[1], acc[mi][1], 0, 0, 0);
            }
            __builtin_amdgcn_s_setprio(0);
            __builtin_amdgcn_s_barrier();                       // (B3)
            // ---- [M3] K-hi, n-hi
            __builtin_amdgcn_s_setprio(1);
#pragma unroll
            for (int mi = 0; mi < 8; ++mi) {
                acc[mi][2] = MFMA(aH[mi], bH[2], acc[mi][2], 0, 0, 0);
                acc[mi][3] = MFMA(aH[mi], bH[3], acc[mi][3], 0, 0, 0);
            }
            __builtin_amdgcn_s_setprio(0);
        }

        // ----- epilogue: dequant + bias (layout col=lane&15, row=(lane>>4)*4+reg)
        {
            float wsv[4], bv[4];
#pragma unroll
            for (int j = 0; j < 4; ++j) {
                const int n = bn * BN + ((j >> 1) << 7) + (wcol << 5) + ((j & 1) << 4) + col;
                wsv[j] = ws[n];
                bv[j]  = bias[n];
            }
#pragma unroll
            for (int i = 0; i < 8; ++i) {
                const int mbase = bm * BM + ((i >> 2) << 7) + (wrow << 6) + ((i & 3) << 4) + rowb;
#pragma unroll
                for (int r = 0; r < 4; ++r) {
                    const int m = mbase + r;
                    const float xsm = xs[m];
                    float* yrow = Y + (size_t)m * N;
#pragma unroll
                    for (int j = 0; j < 4; ++j) {
                        const int n = bn * BN + ((j >> 1) << 7) + (wcol << 5) + ((j & 1) << 4) + col;
                        yrow[n] = (float)acc[i][j][r] * xsm * wsv[j] + bv[j];
                    }
                }
            }
        }

        if (seg == 0) {
#pragma unroll
            for (int i = 0; i < 8; ++i)
#pragma unroll
                for (int j = 0; j < 4; ++j)
                    acc[i][j] = (v4i){0, 0, 0, 0};
        }
    }
#undef AOFF
#undef BOFF
}

// ---------------------------------------------------------------------------
extern "C" void kernel_launch(void* const* d_in, const int* in_sizes, int n_in,
                              void* d_out, int out_size, void* d_ws, size_t ws_size,
                              hipStream_t stream) {
    const float* X    = (const float*)d_in[0];
    const float* W    = (const float*)d_in[1];
    const float* bias = (const float*)d_in[2];
    const float* ss   = (const float*)d_in[3];

    const int DIN  = in_sizes[3];              // 4096
    const int DOUT = in_sizes[2];              // 4096
    const int M    = in_sizes[0] / DIN;        // 8192

    int8_t* Xq = (int8_t*)d_ws;
    int8_t* Wq = Xq + (size_t)M * DIN;
    float*  xs = (float*)(Wq + (size_t)DOUT * DIN);
    float*  ws = xs + M;
    float*  Y  = (float*)d_out;

    quant_kernel<<<M + DOUT, 256, 0, stream>>>(X, W, ss, Xq, xs, Wq, ws, DIN, M);
    gemm_i8_kernel<<<(M / BM) * (DOUT / BN) / 2, 512, 0, stream>>>(Xq, Wq, xs, ws, bias, Y, M, DOUT, DIN);
}